// Round 12
// baseline (575.173 us; speedup 1.0000x reference)
//
#include <hip/hip_runtime.h>
#include <hip/hip_bf16.h>
#include <math.h>

#define LEAKY 0.2f

// ---------------- fp32 tiled GEMM + fused attention scores ----------------
#define BM 64
#define BN 64
#define BK 32
__global__ __launch_bounds__(256) void gemm_att(const float* __restrict__ A,
                                                const float* __restrict__ B,
                                                float* __restrict__ C,
                                                const float* __restrict__ att_s,
                                                const float* __restrict__ att_d,
                                                float* __restrict__ asrc,
                                                float* __restrict__ adst,
                                                int M, int K, int NC) {
    __shared__ float As[BK][BM + 1];
    __shared__ float Bs[BK][BN];
    const int tid = threadIdx.x;
    const int bm = blockIdx.x * BM;
    const int bn = blockIdx.y * BN;
    const int tx = tid & 15, ty = tid >> 4;
    float acc[4][4] = {};
    for (int k0 = 0; k0 < K; k0 += BK) {
        #pragma unroll
        for (int i = 0; i < (BM * BK) / 256; ++i) {
            int idx = tid + i * 256;
            int r = idx >> 5, c = idx & 31;
            int gr = bm + r;
            As[c][r] = (gr < M) ? A[(size_t)gr * K + k0 + c] : 0.f;
        }
        #pragma unroll
        for (int i = 0; i < (BK * BN) / 256; ++i) {
            int idx = tid + i * 256;
            int r = idx >> 6, c = idx & 63;
            Bs[r][c] = B[(size_t)(k0 + r) * NC + bn + c];
        }
        __syncthreads();
        #pragma unroll
        for (int k = 0; k < BK; ++k) {
            float a[4], b[4];
            #pragma unroll
            for (int i = 0; i < 4; ++i) a[i] = As[k][ty * 4 + i];
            #pragma unroll
            for (int j = 0; j < 4; ++j) b[j] = Bs[k][tx * 4 + j];
            #pragma unroll
            for (int i = 0; i < 4; ++i)
                #pragma unroll
                for (int j = 0; j < 4; ++j)
                    acc[i][j] += a[i] * b[j];
        }
        __syncthreads();
    }
    float s_att[4], d_att[4];
    #pragma unroll
    for (int j = 0; j < 4; ++j) {
        s_att[j] = att_s[bn + tx * 4 + j];
        d_att[j] = att_d[bn + tx * 4 + j];
    }
    const int head = bn >> 6;
    const int H = NC >> 6;
    #pragma unroll
    for (int i = 0; i < 4; ++i) {
        int gr = bm + ty * 4 + i;
        float ps = 0.f, pd = 0.f;
        #pragma unroll
        for (int j = 0; j < 4; ++j) {
            ps += acc[i][j] * s_att[j];
            pd += acc[i][j] * d_att[j];
        }
        #pragma unroll
        for (int o = 1; o < 16; o <<= 1) {
            ps += __shfl_xor(ps, o);
            pd += __shfl_xor(pd, o);
        }
        if (gr < M) {
            #pragma unroll
            for (int j = 0; j < 4; ++j)
                C[(size_t)gr * NC + bn + tx * 4 + j] = acc[i][j];
            if (tx == 0) {
                asrc[gr * H + head] = ps;
                adst[gr * H + head] = pd;
            }
        }
    }
}

// ---------------- CSR build ----------------
__global__ __launch_bounds__(256) void count_deg(const int* __restrict__ ei, int E_, int N_,
                                                 int* __restrict__ deg) {
    int eid = blockIdx.x * 256 + threadIdx.x;
    int Etot = E_ + N_;
    if (eid >= Etot) return;
    int dst = (eid < E_) ? ei[E_ + eid] : (eid - E_);
    atomicAdd(&deg[dst], 1);
}

__global__ __launch_bounds__(1024) void scan_offsets(const int* __restrict__ deg,
                                                     int* __restrict__ off, int n) {
    __shared__ int wsum[16];
    int tid = threadIdx.x;
    int lane = tid & 63, w = tid >> 6;
    int chunk = (n + 1023) / 1024;
    int b = tid * chunk;
    int e = min(b + chunk, n);
    int s = 0;
    for (int i = b; i < e; ++i) s += deg[i];
    int v = s;
    #pragma unroll
    for (int o = 1; o < 64; o <<= 1) {
        int t = __shfl_up(v, o);
        if (lane >= o) v += t;
    }
    if (lane == 63) wsum[w] = v;
    __syncthreads();
    if (w == 0) {
        int t = (lane < 16) ? wsum[lane] : 0;
        #pragma unroll
        for (int o = 1; o < 16; o <<= 1) {
            int u = __shfl_up(t, o);
            if (lane >= o) t += u;
        }
        if (lane < 16) wsum[lane] = t;
    }
    __syncthreads();
    int acc = (w > 0 ? wsum[w - 1] : 0) + (v - s);
    for (int i = b; i < e; ++i) { off[i] = acc; acc += deg[i]; }
    if (e == n) off[n] = acc;
}

__global__ __launch_bounds__(256) void scatter_edges(const int* __restrict__ ei, int E_, int N_,
                                                     int* __restrict__ off,
                                                     int* __restrict__ csr) {
    int eid = blockIdx.x * 256 + threadIdx.x;
    int Etot = E_ + N_;
    if (eid >= Etot) return;
    int src, dst;
    if (eid < E_) { src = ei[eid]; dst = ei[E_ + eid]; }
    else          { src = dst = eid - E_; }
    int pos = atomicAdd(&off[dst], 1);
    csr[pos] = src;
}

// ---------------- fused GAT aggregation, 4 heads (wave/node; float4 row gather) ----------------
// Lane l owns channels 4l..4l+3 (head l>>4): ONE dwordx4 per edge covers the whole
// 1KB h-row per wave. Unroll x4 -> 4 dwordx4 in flight. Weights packed wl[slot*4+head]
// (conflict-free broadcast read; the 8-way-conflict write is once per 64 edges).
__global__ __launch_bounds__(256) void gat_agg_h4(const int* __restrict__ off,
                                                  const int* __restrict__ csr,
                                                  const float* __restrict__ asrc,
                                                  const float* __restrict__ adst,
                                                  const float* __restrict__ hsrc,
                                                  const float* __restrict__ bias,
                                                  float* __restrict__ outp, int N_) {
    __shared__ float wls[4][256];   // [wave][slot*4 + head]
    __shared__ int   uls[4][64];
    int wv = threadIdx.x >> 6, lane = threadIdx.x & 63;
    int node = blockIdx.x * 4 + wv;
    if (node >= N_) return;
    int s = node ? off[node - 1] : 0;
    int e = off[node];
    int deg = e - s;
    float4 ad = *(const float4*)(adst + node * 4);
    float* wl = wls[wv];
    int*   ul = uls[wv];
    const int hgrp = lane >> 4;
    const float4* h4p = (const float4*)hsrc;     // row stride 64 float4s
    float4 acc = {0.f, 0.f, 0.f, 0.f};
    float d0 = 0.f, d1 = 0.f, d2 = 0.f, d3 = 0.f;

    if (deg <= 64) {
        // scores stay in registers between max and exp
        float e0 = -INFINITY, e1 = -INFINITY, e2 = -INFINITY, e3 = -INFINITY;
        int u = 0;
        if (lane < deg) {
            u = csr[s + lane];
            float4 as = *(const float4*)(asrc + u * 4);
            e0 = as.x + ad.x; e0 = e0 > 0.f ? e0 : LEAKY * e0;
            e1 = as.y + ad.y; e1 = e1 > 0.f ? e1 : LEAKY * e1;
            e2 = as.z + ad.z; e2 = e2 > 0.f ? e2 : LEAKY * e2;
            e3 = as.w + ad.w; e3 = e3 > 0.f ? e3 : LEAKY * e3;
        }
        float m0 = e0, m1 = e1, m2 = e2, m3 = e3;
        #pragma unroll
        for (int o = 32; o > 0; o >>= 1) {
            m0 = fmaxf(m0, __shfl_xor(m0, o));
            m1 = fmaxf(m1, __shfl_xor(m1, o));
            m2 = fmaxf(m2, __shfl_xor(m2, o));
            m3 = fmaxf(m3, __shfl_xor(m3, o));
        }
        if (lane < deg) {
            float w0 = __expf(e0 - m0), w1 = __expf(e1 - m1);
            float w2 = __expf(e2 - m2), w3 = __expf(e3 - m3);
            d0 = w0; d1 = w1; d2 = w2; d3 = w3;
            ((float4*)wl)[lane] = make_float4(w0, w1, w2, w3);
            ul[lane] = u;
        }
        int j = 0;
        for (; j + 4 <= deg; j += 4) {
            int u0 = ul[j], u1 = ul[j + 1], u2 = ul[j + 2], u3 = ul[j + 3];
            float W0 = wl[(j    ) * 4 + hgrp];
            float W1 = wl[(j + 1) * 4 + hgrp];
            float W2 = wl[(j + 2) * 4 + hgrp];
            float W3 = wl[(j + 3) * 4 + hgrp];
            float4 g0 = h4p[(size_t)u0 * 64 + lane];
            float4 g1 = h4p[(size_t)u1 * 64 + lane];
            float4 g2 = h4p[(size_t)u2 * 64 + lane];
            float4 g3 = h4p[(size_t)u3 * 64 + lane];
            acc.x += W0 * g0.x; acc.y += W0 * g0.y; acc.z += W0 * g0.z; acc.w += W0 * g0.w;
            acc.x += W1 * g1.x; acc.y += W1 * g1.y; acc.z += W1 * g1.z; acc.w += W1 * g1.w;
            acc.x += W2 * g2.x; acc.y += W2 * g2.y; acc.z += W2 * g2.z; acc.w += W2 * g2.w;
            acc.x += W3 * g3.x; acc.y += W3 * g3.y; acc.z += W3 * g3.z; acc.w += W3 * g3.w;
        }
        for (; j < deg; ++j) {
            int u0 = ul[j];
            float W0 = wl[j * 4 + hgrp];
            float4 g0 = h4p[(size_t)u0 * 64 + lane];
            acc.x += W0 * g0.x; acc.y += W0 * g0.y; acc.z += W0 * g0.z; acc.w += W0 * g0.w;
        }
    } else {
        // general path: strided max, then 64-edge chunks
        float m0 = -INFINITY, m1 = -INFINITY, m2 = -INFINITY, m3 = -INFINITY;
        for (int i = s + lane; i < e; i += 64) {
            int u = csr[i];
            float4 as = *(const float4*)(asrc + u * 4);
            float t;
            t = as.x + ad.x; t = t > 0.f ? t : LEAKY * t; m0 = fmaxf(m0, t);
            t = as.y + ad.y; t = t > 0.f ? t : LEAKY * t; m1 = fmaxf(m1, t);
            t = as.z + ad.z; t = t > 0.f ? t : LEAKY * t; m2 = fmaxf(m2, t);
            t = as.w + ad.w; t = t > 0.f ? t : LEAKY * t; m3 = fmaxf(m3, t);
        }
        #pragma unroll
        for (int o = 32; o > 0; o >>= 1) {
            m0 = fmaxf(m0, __shfl_xor(m0, o));
            m1 = fmaxf(m1, __shfl_xor(m1, o));
            m2 = fmaxf(m2, __shfl_xor(m2, o));
            m3 = fmaxf(m3, __shfl_xor(m3, o));
        }
        for (int base = s; base < e; base += 64) {
            int cnt = min(64, e - base);
            if (lane < cnt) {
                int u = csr[base + lane];
                float4 as = *(const float4*)(asrc + u * 4);
                float t, w0, w1, w2, w3;
                t = as.x + ad.x; t = t > 0.f ? t : LEAKY * t; w0 = __expf(t - m0); d0 += w0;
                t = as.y + ad.y; t = t > 0.f ? t : LEAKY * t; w1 = __expf(t - m1); d1 += w1;
                t = as.z + ad.z; t = t > 0.f ? t : LEAKY * t; w2 = __expf(t - m2); d2 += w2;
                t = as.w + ad.w; t = t > 0.f ? t : LEAKY * t; w3 = __expf(t - m3); d3 += w3;
                ((float4*)wl)[lane] = make_float4(w0, w1, w2, w3);
                ul[lane] = u;
            }
            int j = 0;
            for (; j + 4 <= cnt; j += 4) {
                int u0 = ul[j], u1 = ul[j + 1], u2 = ul[j + 2], u3 = ul[j + 3];
                float W0 = wl[(j    ) * 4 + hgrp];
                float W1 = wl[(j + 1) * 4 + hgrp];
                float W2 = wl[(j + 2) * 4 + hgrp];
                float W3 = wl[(j + 3) * 4 + hgrp];
                float4 g0 = h4p[(size_t)u0 * 64 + lane];
                float4 g1 = h4p[(size_t)u1 * 64 + lane];
                float4 g2 = h4p[(size_t)u2 * 64 + lane];
                float4 g3 = h4p[(size_t)u3 * 64 + lane];
                acc.x += W0 * g0.x; acc.y += W0 * g0.y; acc.z += W0 * g0.z; acc.w += W0 * g0.w;
                acc.x += W1 * g1.x; acc.y += W1 * g1.y; acc.z += W1 * g1.z; acc.w += W1 * g1.w;
                acc.x += W2 * g2.x; acc.y += W2 * g2.y; acc.z += W2 * g2.z; acc.w += W2 * g2.w;
                acc.x += W3 * g3.x; acc.y += W3 * g3.y; acc.z += W3 * g3.z; acc.w += W3 * g3.w;
            }
            for (; j < cnt; ++j) {
                int u0 = ul[j];
                float W0 = wl[j * 4 + hgrp];
                float4 g0 = h4p[(size_t)u0 * 64 + lane];
                acc.x += W0 * g0.x; acc.y += W0 * g0.y; acc.z += W0 * g0.z; acc.w += W0 * g0.w;
            }
        }
    }
    // denominator tree-sums (inactive lanes contributed 0)
    #pragma unroll
    for (int o = 32; o > 0; o >>= 1) {
        d0 += __shfl_xor(d0, o);
        d1 += __shfl_xor(d1, o);
        d2 += __shfl_xor(d2, o);
        d3 += __shfl_xor(d3, o);
    }
    float dh = hgrp == 0 ? d0 : hgrp == 1 ? d1 : hgrp == 2 ? d2 : d3;
    float rdh = 1.f / (dh + 1e-16f);
    float4 bi = *(const float4*)(bias + lane * 4);
    float4 v;
    v.x = acc.x * rdh + bi.x; v.x = v.x > 0.f ? v.x : expm1f(v.x);
    v.y = acc.y * rdh + bi.y; v.y = v.y > 0.f ? v.y : expm1f(v.y);
    v.z = acc.z * rdh + bi.z; v.z = v.z > 0.f ? v.z : expm1f(v.z);
    v.w = acc.w * rdh + bi.w; v.w = v.w > 0.f ? v.w : expm1f(v.w);
    ((float4*)(outp + (size_t)node * 256))[lane] = v;
}

// ---------------- fused GAT aggregation, 1 head (wave/node; 16-lane-per-edge float4) ----------------
// 16 lanes x 16B cover one 256B row; 4 edges per wave-iteration; 16-edge unroll
// (4 dwordx4 in flight). Cross-group combine via shfl_xor(16/32).
__global__ __launch_bounds__(256) void gat_agg_h1(const int* __restrict__ off,
                                                  const int* __restrict__ csr,
                                                  const float* __restrict__ asrc,
                                                  const float* __restrict__ adst,
                                                  const float* __restrict__ g,
                                                  const float* __restrict__ bias,
                                                  float* __restrict__ outp, int N_) {
    __shared__ float wls[4][64];
    __shared__ int   uls[4][64];
    int wv = threadIdx.x >> 6, lane = threadIdx.x & 63;
    int node = blockIdx.x * 4 + wv;
    if (node >= N_) return;
    int s = node ? off[node - 1] : 0;
    int e = off[node];
    int deg = e - s;
    float ad = adst[node];
    float* wl = wls[wv];
    int*   ul = uls[wv];
    const int sub = lane >> 4;       // which edge of the quad
    const int cl  = lane & 15;       // channel quad: channels 4cl..4cl+3
    const float4* g4 = (const float4*)g;   // row stride 16 float4s
    float4 acc = {0.f, 0.f, 0.f, 0.f};
    float d = 0.f;

    if (deg <= 64) {
        float ev = -INFINITY;
        int u = 0;
        if (lane < deg) {
            u = csr[s + lane];
            ev = asrc[u] + ad;
            ev = ev > 0.f ? ev : LEAKY * ev;
        }
        float mm = ev;
        #pragma unroll
        for (int o = 32; o > 0; o >>= 1) mm = fmaxf(mm, __shfl_xor(mm, o));
        if (lane < deg) {
            float w = __expf(ev - mm);
            d = w;
            wl[lane] = w;
            ul[lane] = u;
        }
        int j = 0;
        for (; j + 16 <= deg; j += 16) {
            int ua = ul[j + sub], ub = ul[j + 4 + sub], uc = ul[j + 8 + sub], ud = ul[j + 12 + sub];
            float Wa = wl[j + sub], Wb = wl[j + 4 + sub], Wc = wl[j + 8 + sub], Wd = wl[j + 12 + sub];
            float4 ga = g4[(size_t)ua * 16 + cl];
            float4 gb = g4[(size_t)ub * 16 + cl];
            float4 gc = g4[(size_t)uc * 16 + cl];
            float4 gd = g4[(size_t)ud * 16 + cl];
            acc.x += Wa * ga.x; acc.y += Wa * ga.y; acc.z += Wa * ga.z; acc.w += Wa * ga.w;
            acc.x += Wb * gb.x; acc.y += Wb * gb.y; acc.z += Wb * gb.z; acc.w += Wb * gb.w;
            acc.x += Wc * gc.x; acc.y += Wc * gc.y; acc.z += Wc * gc.z; acc.w += Wc * gc.w;
            acc.x += Wd * gd.x; acc.y += Wd * gd.y; acc.z += Wd * gd.z; acc.w += Wd * gd.w;
        }
        for (; j + 4 <= deg; j += 4) {
            int ua = ul[j + sub];
            float Wa = wl[j + sub];
            float4 ga = g4[(size_t)ua * 16 + cl];
            acc.x += Wa * ga.x; acc.y += Wa * ga.y; acc.z += Wa * ga.z; acc.w += Wa * ga.w;
        }
        if (sub < deg - j) {
            int ua = ul[j + sub];
            float Wa = wl[j + sub];
            float4 ga = g4[(size_t)ua * 16 + cl];
            acc.x += Wa * ga.x; acc.y += Wa * ga.y; acc.z += Wa * ga.z; acc.w += Wa * ga.w;
        }
    } else {
        float mm = -INFINITY;
        for (int i = s + lane; i < e; i += 64) {
            float t = asrc[csr[i]] + ad;
            t = t > 0.f ? t : LEAKY * t;
            mm = fmaxf(mm, t);
        }
        #pragma unroll
        for (int o = 32; o > 0; o >>= 1) mm = fmaxf(mm, __shfl_xor(mm, o));
        for (int base = s; base < e; base += 64) {
            int cnt = min(64, e - base);
            if (lane < cnt) {
                int u = csr[base + lane];
                float t = asrc[u] + ad;
                t = t > 0.f ? t : LEAKY * t;
                float w = __expf(t - mm);
                d += w;
                wl[lane] = w;
                ul[lane] = u;
            }
            int j = 0;
            for (; j + 4 <= cnt; j += 4) {
                int ua = ul[j + sub];
                float Wa = wl[j + sub];
                float4 ga = g4[(size_t)ua * 16 + cl];
                acc.x += Wa * ga.x; acc.y += Wa * ga.y; acc.z += Wa * ga.z; acc.w += Wa * ga.w;
            }
            if (sub < cnt - j) {
                int ua = ul[j + sub];
                float Wa = wl[j + sub];
                float4 ga = g4[(size_t)ua * 16 + cl];
                acc.x += Wa * ga.x; acc.y += Wa * ga.y; acc.z += Wa * ga.z; acc.w += Wa * ga.w;
            }
        }
    }
    // combine the 4 edge-subgroups: channel c lives in lanes {cl, cl+16, cl+32, cl+48}
    acc.x += __shfl_xor(acc.x, 16); acc.x += __shfl_xor(acc.x, 32);
    acc.y += __shfl_xor(acc.y, 16); acc.y += __shfl_xor(acc.y, 32);
    acc.z += __shfl_xor(acc.z, 16); acc.z += __shfl_xor(acc.z, 32);
    acc.w += __shfl_xor(acc.w, 16); acc.w += __shfl_xor(acc.w, 32);
    #pragma unroll
    for (int o = 32; o > 0; o >>= 1) d += __shfl_xor(d, o);
    if (sub == 0) {
        float rd = 1.f / (d + 1e-16f);
        float4 bi = ((const float4*)bias)[cl];
        float4 v;
        v.x = acc.x * rd + bi.x; v.x = v.x > 0.f ? v.x : expm1f(v.x);
        v.y = acc.y * rd + bi.y; v.y = v.y > 0.f ? v.y : expm1f(v.y);
        v.z = acc.z * rd + bi.z; v.z = v.z > 0.f ? v.z : expm1f(v.z);
        v.w = acc.w * rd + bi.w; v.w = v.w > 0.f ? v.w : expm1f(v.w);
        ((float4*)(outp + (size_t)node * 64))[cl] = v;
    }
}

extern "C" void kernel_launch(void* const* d_in, const int* in_sizes, int n_in,
                              void* d_out, int out_size, void* d_ws, size_t ws_size,
                              hipStream_t stream) {
    const float* x        = (const float*)d_in[0];
    const int*   ei       = (const int*)d_in[1];     // int32 (harness: integer -> const int*)
    // d_in[2] = edge_attr (unused: PyG GATConv with edge_dim=None)
    const float* W1       = (const float*)d_in[3];
    const float* att_src1 = (const float*)d_in[4];
    const float* att_dst1 = (const float*)d_in[5];
    const float* b1       = (const float*)d_in[6];
    const float* W2       = (const float*)d_in[7];
    const float* att_src2 = (const float*)d_in[8];
    const float* att_dst2 = (const float*)d_in[9];
    const float* b2       = (const float*)d_in[10];
    float* out = (float*)d_out;

    const int N = in_sizes[0] / 128;     // 50000
    const int E = in_sizes[1] / 2;       // 800000
    const int Etot = E + N;

    float* ws    = (float*)d_ws;
    float* h1    = ws;                         // N*256  (L1 GEMM out; dead after gat_agg_h4)
    float* h2    = h1 + (size_t)N * 256;       // N*256  (L1 out = L2 GEMM in)
    float* g2    = h1;                         // N*64   (aliases h1 — dead by then)
    float* asrc1 = h2 + (size_t)N * 256;       // N*4
    float* adst1 = asrc1 + (size_t)N * 4;      // N*4
    float* asrc2 = adst1 + (size_t)N * 4;      // N
    float* adst2 = asrc2 + N;                  // N
    int*   deg   = (int*)(adst2 + N);          // N+1
    int*   off   = deg + (N + 1);              // N+1 (scan out; scatter cursor; bucket ends)
    int*   csr   = off + (N + 1);              // Etot

    // ---- CSR build (graph identical for both layers) ----
    hipMemsetAsync(deg, 0, (N + 1) * sizeof(int), stream);
    count_deg<<<(Etot + 255) / 256, 256, 0, stream>>>(ei, E, N, deg);
    scan_offsets<<<1, 1024, 0, stream>>>(deg, off, N);
    scatter_edges<<<(Etot + 255) / 256, 256, 0, stream>>>(ei, E, N, off, csr);

    // ---- layer 1 ----
    {
        dim3 g((N + BM - 1) / BM, 256 / BN);
        gemm_att<<<g, 256, 0, stream>>>(x, W1, h1, att_src1, att_dst1, asrc1, adst1, N, 128, 256);
    }
    gat_agg_h4<<<(N + 3) / 4, 256, 0, stream>>>(off, csr, asrc1, adst1, h1, b1, h2, N);

    // ---- layer 2 ----
    {
        dim3 g((N + BM - 1) / BM, 64 / BN);
        gemm_att<<<g, 256, 0, stream>>>(h2, W2, g2, att_src2, att_dst2, asrc2, adst2, N, 256, 64);
    }
    gat_agg_h1<<<(N + 3) / 4, 256, 0, stream>>>(off, csr, asrc2, adst2, g2, b2, out, N);
}